// Round 18
// baseline (269.463 us; speedup 1.0000x reference)
//
#include <hip/hip_runtime.h>
#include <hip/hip_fp16.h>
#include <math.h>

// Problem constants
constexpr int S_IN = 32, V_IN = 16, INVD = 16;
constexpr int S_MSG = S_IN + V_IN;           // 48
constexpr int V_MSG = S_IN + V_IN;           // 48
constexpr int NFAC  = S_MSG + V_MSG;         // 96
constexpr int S_OUT = 32, V_OUT = 16;
constexpr int OUT_PER_NODE = S_OUT + V_OUT * 3;  // 80
constexpr float ISQRT3 = 0.57735026918962576f;
constexpr float ISQ48  = 0.14433756729740643f;

// prepped-weight layout (in shorts): W0T[64][40] | W1T[64][72] | W2T[96][72] | WLT[48][72]
constexpr int PW0 = 0, PW1 = 2560, PW2 = 7168, PWL = 14080, PWTOT = 17536;

typedef _Float16 f16x8 __attribute__((ext_vector_type(8)));
typedef __attribute__((ext_vector_type(4))) float f32x4;

__device__ __forceinline__ float silu_f(float x) {
    return x * __builtin_amdgcn_rcpf(1.0f + __expf(-x));
}
__device__ __forceinline__ unsigned int hpack2(float a, float b) {
    __half2 h = __floats2half2_rn(a, b);        // v_cvt_pkrtz_f16_f32
    return *reinterpret_cast<unsigned int*>(&h);
}
__device__ __forceinline__ unsigned short f2h(float f) {
    __half h = __float2half_rn(f);
    return __half_as_ushort(h);
}
__device__ __forceinline__ float h2f(unsigned short u) {
    return __half2float(__ushort_as_half(u));
}
__device__ __forceinline__ float lo16f(unsigned int u) { return h2f((unsigned short)(u & 0xffffu)); }
__device__ __forceinline__ float hi16f(unsigned int u) { return h2f((unsigned short)(u >> 16)); }
__device__ __forceinline__ unsigned int pkmul(unsigned int a, unsigned int b) {
    __half2 ha = *reinterpret_cast<__half2*>(&a);
    __half2 hb = *reinterpret_cast<__half2*>(&b);
    __half2 hc = __hmul2(ha, hb);               // v_pk_mul_f16
    return *reinterpret_cast<unsigned int*>(&hc);
}
__device__ __forceinline__ float2 up2(unsigned int u) {
    __half2 h = *reinterpret_cast<__half2*>(&u);
    return __half22float2(h);
}

// ---------------------------------------------------------------------------
// hist + prep fused
// ---------------------------------------------------------------------------
__global__ __launch_bounds__(256) void hist_prep(
    const int* __restrict__ edst, int* __restrict__ deg, int E,
    const float* __restrict__ W0, const float* __restrict__ W1,
    const float* __restrict__ W2, const float* __restrict__ WLs,
    const float* __restrict__ WLv,
    const float* __restrict__ ns, const float* __restrict__ nv,
    unsigned short* __restrict__ pW,
    unsigned short* __restrict__ pNS,
    unsigned short* __restrict__ pNV,
    int Nn)
{
    int i = blockIdx.x * 256 + threadIdx.x;
    if (i < E) atomicAdd(&deg[edst[i]], 1);

    int nNS = Nn * 4;
    int nNV = Nn * 6;
    if (i < PWTOT) {
        float v = 0.0f;
        if (i < PW1) {
            int j = i / 40, k = i - 40 * j;
            if (k < INVD) v = W0[k * 64 + j];
        } else if (i < PW2) {
            int t = i - PW1; int j = t / 72, k = t - 72 * j;
            if (k < 64) v = W1[k * 64 + j];
        } else if (i < PWL) {
            int t = i - PW2; int j = t / 72, k = t - 72 * j;
            if (k < 64) v = W2[k * 96 + j];
        } else {
            int t = i - PWL; int j = t / 72, k = t - 72 * j;
            if (k < 48) v = (j < 32) ? WLs[k * S_OUT + j] : WLv[k * V_OUT + (j - 32)];
        }
        pW[i] = f2h(v);
    } else if (i < PWTOT + nNS) {
        int g = i - PWTOT;
        const float4* s4 = reinterpret_cast<const float4*>(ns + (size_t)g * 8);
        float4 a = s4[0], b = s4[1];
        *reinterpret_cast<uint4*>(pNS + (size_t)g * 8) =
            make_uint4(hpack2(a.x, a.y), hpack2(a.z, a.w), hpack2(b.x, b.y), hpack2(b.z, b.w));
    } else if (i < PWTOT + nNS + nNV) {
        int g = i - PWTOT - nNS;
        const float4* s4 = reinterpret_cast<const float4*>(nv + (size_t)g * 8);
        float4 a = s4[0], b = s4[1];
        *reinterpret_cast<uint4*>(pNV + (size_t)g * 8) =
            make_uint4(hpack2(a.x, a.y), hpack2(a.z, a.w), hpack2(b.x, b.y), hpack2(b.z, b.w));
    }
}

// ---------------------------------------------------------------------------
// single-block scan: deg -> exclusive prefix (cursor)
// ---------------------------------------------------------------------------
__global__ __launch_bounds__(1024) void scan1(
    const int* __restrict__ deg, int* __restrict__ cursor, int Nn)
{
    const int T = 1024;
    int t = threadIdx.x;
    int chunk = (Nn + T - 1) / T;
    int lo = t * chunk;
    int hi = lo + chunk; if (hi > Nn) hi = Nn;
    int s = 0;
    for (int i = lo; i < hi; i++) s += deg[i];
    __shared__ int ps[T];
    ps[t] = s;
    __syncthreads();
    for (int off = 1; off < T; off <<= 1) {
        int v = (t >= off) ? ps[t - off] : 0;
        __syncthreads();
        ps[t] += v;
        __syncthreads();
    }
    int base = (t > 0) ? ps[t - 1] : 0;
    for (int i = lo; i < hi; i++) {
        cursor[i] = base;
        base += deg[i];
    }
}

// Fat scatter: 48B per-edge record at permuted position (3 x uint4).
// r0,r1 = einv f16 x16 (32B)
// r2 = { cut_h|esh0_h, esh1_h|esh2_h, src, dst } (16B)
__global__ __launch_bounds__(256) void scatter_permute(
    const int*   __restrict__ edst,
    const int*   __restrict__ esrc,
    const float* __restrict__ ecut,
    const float* __restrict__ esh,
    const float* __restrict__ einv,
    int* __restrict__ cursor,
    uint4* __restrict__ pedge,
    int E)
{
    int e = blockIdx.x * 256 + threadIdx.x;
    if (e >= E) return;
    int d = edst[e];
    int pos = atomicAdd(&cursor[d], 1);

    const float4* xr = reinterpret_cast<const float4*>(einv + (size_t)e * INVD);
    float4 a = xr[0], b = xr[1], c = xr[2], f = xr[3];
    uint4 r0 = make_uint4(hpack2(a.x, a.y), hpack2(a.z, a.w), hpack2(b.x, b.y), hpack2(b.z, b.w));
    uint4 r1 = make_uint4(hpack2(c.x, c.y), hpack2(c.z, c.w), hpack2(f.x, f.y), hpack2(f.z, f.w));
    uint4 r2 = make_uint4(hpack2(ecut[e], esh[(size_t)e * 3 + 0]),
                          hpack2(esh[(size_t)e * 3 + 1], esh[(size_t)e * 3 + 2]),
                          (unsigned int)esrc[e], (unsigned int)d);

    uint4* dst = pedge + (size_t)pos * 3;
    dst[0] = r0; dst[1] = r1; dst[2] = r2;
}

// ---------------------------------------------------------------------------
// MEGA kernel v10: 32 KiB LDS (5 blocks/CU); split prefetch (1 row type per
// thread); PARALLEL phase-B staging (WLT+Fns+Fnv coexist); 6 barriers.
// LDS maps (bytes):
//   A : act[128][72] @0 (18432) | W0T+W1T @18432 (14336)
//   L3: W2T[96][72] @18432 (13824)
//   B : WLT[48][72] @0 (6912) | Fns[128][40] @6912 (10240)
//       Fnv0 @17152, Fnv1 @22272, Fnv2 @27392 (each 5120)
//       M[128][72] @6912 (18432, overlays Fns/Fnv0/Fnv1 after frag loads)
//   C : redh[128][84]fp16 @0 (21504)
// ---------------------------------------------------------------------------
__global__ __launch_bounds__(256, 5) void edge_mega(
    const uint4* __restrict__ pedge,
    const unsigned short* __restrict__ pW,
    const unsigned short* __restrict__ pNS,
    const unsigned short* __restrict__ pNV,
    float* __restrict__ out,
    int E)
{
    __shared__ __align__(16) unsigned char smem[32768];

    unsigned short* act  = (unsigned short*)(smem + 0);      // [128][72]
    unsigned short* sW0T = (unsigned short*)(smem + 18432);  // [64][40]
    unsigned short* sW1T = (unsigned short*)(smem + 23552);  // [64][72]
    unsigned short* sW2T = (unsigned short*)(smem + 18432);  // [96][72]
    unsigned short* sWLT = (unsigned short*)(smem + 0);      // [48][72]
    unsigned short* Fns  = (unsigned short*)(smem + 6912);   // [128][40]
    unsigned short* Fnv0 = (unsigned short*)(smem + 17152);  // [128][20]
    unsigned short* Fnv1 = (unsigned short*)(smem + 22272);  // [128][20]
    unsigned short* Fnv2 = (unsigned short*)(smem + 27392);  // [128][20]
    unsigned short* M    = (unsigned short*)(smem + 6912);   // [128][72]
    unsigned short* redh = (unsigned short*)(smem + 0);      // [128][84] fp16

    const int tid = threadIdx.x;
    const int pbase = blockIdx.x * 128;
    const int p1 = E;

    const int lane = tid & 63;
    const int w    = tid >> 6;
    const int lr   = lane & 15;
    const int lg   = lane >> 4;
    const int eb0  = w * 32 + lr;
    const int eb1  = eb0 + 16;
    const int pA   = pbase + eb0;
    const int pB   = pbase + eb1;

    // ============ PREFETCH (split: half=0 -> ns row, half=1 -> nv row) ======
    const uint4 rA2 = pedge[(size_t)(pA < p1 ? pA : p1 - 1) * 3 + 2];
    const uint4 rB2 = pedge[(size_t)(pB < p1 ? pB : p1 - 1) * 3 + 2];
    const float cutA = lo16f(rA2.x);
    const float ev0a = hi16f(rA2.x), ev1a = lo16f(rA2.y), ev2a = hi16f(rA2.y);
    const float cutB = lo16f(rB2.x);
    const float ev0b = hi16f(rB2.x), ev1b = lo16f(rB2.y), ev2b = hi16f(rB2.y);

    const int t2 = tid >> 1, half = tid & 1;
    int dS;
    uint4 pf0, pf1, pf2, pf3, pf4, pf5;
    {
        int pS = pbase + t2; if (pS >= p1) pS = p1 - 1;
        uint4 r2 = pedge[(size_t)pS * 3 + 2];
        int sS = (int)r2.z;
        dS = (int)r2.w;
        if (half == 0) {
            const uint4* nr = reinterpret_cast<const uint4*>(pNS + (size_t)sS * 32);
            pf0 = nr[0]; pf1 = nr[1]; pf2 = nr[2]; pf3 = nr[3];
        } else {
            const uint4* vr = reinterpret_cast<const uint4*>(pNV + (size_t)sS * 48);
            pf0 = vr[0]; pf1 = vr[1]; pf2 = vr[2]; pf3 = vr[3]; pf4 = vr[4]; pf5 = vr[5];
        }
    }

    const uint4* wsrc = reinterpret_cast<const uint4*>(pW);

    // ---- stage W0T+W1T (896 uint4) + X into act ----
    {
        uint4* s4 = reinterpret_cast<uint4*>(smem + 18432);
        #pragma unroll 2
        for (int i = tid; i < 896; i += 256) s4[i] = wsrc[i];
    }
    if (tid < 128) {
        int p = pbase + tid; if (p >= p1) p = p1 - 1;
        const uint4* rec = pedge + (size_t)p * 3;
        uint4 r0 = rec[0], r1 = rec[1];
        uint4* r4 = reinterpret_cast<uint4*>(&act[tid * 72]);
        r4[0] = r0;
        r4[1] = r1;
        r4[2] = make_uint4(0u, 0u, 0u, 0u);
        r4[3] = make_uint4(0u, 0u, 0u, 0u);
    }
    __syncthreads();   // B1

    const f32x4 zero4 = {0.f, 0.f, 0.f, 0.f};

    // ---- Layer 1: h1 = silu((X@W0)/4); read-then-write, wave-local ----
    {
        f16x8 b0 = *(const f16x8*)&act[eb0 * 72 + lg * 8];
        f16x8 b1 = *(const f16x8*)&act[eb1 * 72 + lg * 8];
        #pragma unroll
        for (int jt = 0; jt < 4; jt++) {
            f16x8 a = *(const f16x8*)&sW0T[(jt * 16 + lr) * 40 + lg * 8];
            f32x4 d0 = __builtin_amdgcn_mfma_f32_16x16x32_f16(a, b0, zero4, 0, 0, 0);
            f32x4 d1 = __builtin_amdgcn_mfma_f32_16x16x32_f16(a, b1, zero4, 0, 0, 0);
            unsigned int u0 = hpack2(silu_f(d0[0] * 0.25f), silu_f(d0[1] * 0.25f));
            unsigned int u1 = hpack2(silu_f(d0[2] * 0.25f), silu_f(d0[3] * 0.25f));
            *(uint2*)&act[eb0 * 72 + jt * 16 + lg * 4] = make_uint2(u0, u1);
            u0 = hpack2(silu_f(d1[0] * 0.25f), silu_f(d1[1] * 0.25f));
            u1 = hpack2(silu_f(d1[2] * 0.25f), silu_f(d1[3] * 0.25f));
            *(uint2*)&act[eb1 * 72 + jt * 16 + lg * 4] = make_uint2(u0, u1);
        }
    }

    // ---- Layer 2: h2 = silu((h1@W1)/8); wave-local ----
    {
        f16x8 b00 = *(const f16x8*)&act[eb0 * 72 +      lg * 8];
        f16x8 b01 = *(const f16x8*)&act[eb0 * 72 + 32 + lg * 8];
        f16x8 b10 = *(const f16x8*)&act[eb1 * 72 +      lg * 8];
        f16x8 b11 = *(const f16x8*)&act[eb1 * 72 + 32 + lg * 8];
        #pragma unroll
        for (int jt = 0; jt < 4; jt++) {
            f16x8 a0 = *(const f16x8*)&sW1T[(jt * 16 + lr) * 72 +      lg * 8];
            f16x8 a1 = *(const f16x8*)&sW1T[(jt * 16 + lr) * 72 + 32 + lg * 8];
            f32x4 d0 = __builtin_amdgcn_mfma_f32_16x16x32_f16(a0, b00, zero4, 0, 0, 0);
            d0 = __builtin_amdgcn_mfma_f32_16x16x32_f16(a1, b01, d0, 0, 0, 0);
            f32x4 d1 = __builtin_amdgcn_mfma_f32_16x16x32_f16(a0, b10, zero4, 0, 0, 0);
            d1 = __builtin_amdgcn_mfma_f32_16x16x32_f16(a1, b11, d1, 0, 0, 0);
            unsigned int u0 = hpack2(silu_f(d0[0] * 0.125f), silu_f(d0[1] * 0.125f));
            unsigned int u1 = hpack2(silu_f(d0[2] * 0.125f), silu_f(d0[3] * 0.125f));
            *(uint2*)&act[eb0 * 72 + jt * 16 + lg * 4] = make_uint2(u0, u1);
            u0 = hpack2(silu_f(d1[0] * 0.125f), silu_f(d1[1] * 0.125f));
            u1 = hpack2(silu_f(d1[2] * 0.125f), silu_f(d1[3] * 0.125f));
            *(uint2*)&act[eb1 * 72 + jt * 16 + lg * 4] = make_uint2(u0, u1);
        }
    }

    __syncthreads();   // B2: W0T/W1T reads done
    {
        uint4* a14 = reinterpret_cast<uint4*>(smem + 18432);
        const uint4* w2s = wsrc + 896;
        #pragma unroll 2
        for (int i = tid; i < 864; i += 256) a14[i] = w2s[i];
    }
    __syncthreads();   // B3: W2T staged

    // ---- Layer 3: fac -> registers ----
    float fac0[6][4], fac1[6][4];
    {
        f16x8 b00 = *(const f16x8*)&act[eb0 * 72 +      lg * 8];
        f16x8 b01 = *(const f16x8*)&act[eb0 * 72 + 32 + lg * 8];
        f16x8 b10 = *(const f16x8*)&act[eb1 * 72 +      lg * 8];
        f16x8 b11 = *(const f16x8*)&act[eb1 * 72 + 32 + lg * 8];
        float K0 = cutA * 0.125f * ISQ48;
        float K1 = cutB * 0.125f * ISQ48;
        #pragma unroll
        for (int jt = 0; jt < 6; jt++) {
            f16x8 a0 = *(const f16x8*)&sW2T[(jt * 16 + lr) * 72 +      lg * 8];
            f16x8 a1 = *(const f16x8*)&sW2T[(jt * 16 + lr) * 72 + 32 + lg * 8];
            f32x4 d0 = __builtin_amdgcn_mfma_f32_16x16x32_f16(a0, b00, zero4, 0, 0, 0);
            d0 = __builtin_amdgcn_mfma_f32_16x16x32_f16(a1, b01, d0, 0, 0, 0);
            f32x4 d1 = __builtin_amdgcn_mfma_f32_16x16x32_f16(a0, b10, zero4, 0, 0, 0);
            d1 = __builtin_amdgcn_mfma_f32_16x16x32_f16(a1, b11, d1, 0, 0, 0);
            float s0 = (jt == 0) ? K0 * ISQRT3 : K0;
            float s1 = (jt == 0) ? K1 * ISQRT3 : K1;
            #pragma unroll
            for (int q = 0; q < 4; q++) {
                fac0[jt][q] = d0[q] * s0;
                fac1[jt][q] = d1[q] * s1;
            }
        }
    }
    __syncthreads();   // B4: act + W2T dead

    // ---- PARALLEL stage: WLT (all threads) + Fns (half=0) + Fnv (half=1) ----
    {
        uint4* wl4 = reinterpret_cast<uint4*>(smem);           // WLT @0
        const uint4* wls = wsrc + 896 + 864;
        #pragma unroll 2
        for (int i = tid; i < 432; i += 256) wl4[i] = wls[i];

        if (half == 0) {
            uint4* d4 = reinterpret_cast<uint4*>(&Fns[t2 * 40]);
            d4[0] = pf0; d4[1] = pf1;
            uint4* d4b = reinterpret_cast<uint4*>(&Fns[t2 * 40 + 16]);
            d4b[0] = pf2; d4b[1] = pf3;
        } else {
            unsigned int wb[24];
            wb[0]=pf0.x; wb[1]=pf0.y; wb[2]=pf0.z; wb[3]=pf0.w;
            wb[4]=pf1.x; wb[5]=pf1.y; wb[6]=pf1.z; wb[7]=pf1.w;
            wb[8]=pf2.x; wb[9]=pf2.y; wb[10]=pf2.z; wb[11]=pf2.w;
            wb[12]=pf3.x; wb[13]=pf3.y; wb[14]=pf3.z; wb[15]=pf3.w;
            wb[16]=pf4.x; wb[17]=pf4.y; wb[18]=pf4.z; wb[19]=pf4.w;
            wb[20]=pf5.x; wb[21]=pf5.y; wb[22]=pf5.z; wb[23]=pf5.w;
            #pragma unroll
            for (int i = 0; i < 3; i++) {
                unsigned short* FnvI = (i == 0) ? Fnv0 : ((i == 1) ? Fnv1 : Fnv2);
                unsigned int ow[8];
                #pragma unroll
                for (int wd = 0; wd < 8; wd++) {
                    int kLo = 6 * wd + i;
                    int kHi = 6 * wd + 3 + i;
                    unsigned int lo = (kLo & 1) ? (wb[kLo >> 1] >> 16) : (wb[kLo >> 1] & 0xffffu);
                    unsigned int hi = (kHi & 1) ? (wb[kHi >> 1] >> 16) : (wb[kHi >> 1] & 0xffffu);
                    ow[wd] = lo | (hi << 16);
                }
                uint2* d2 = reinterpret_cast<uint2*>(&FnvI[t2 * 20]);
                d2[0] = make_uint2(ow[0], ow[1]);
                d2[1] = make_uint2(ow[2], ow[3]);
                d2[2] = make_uint2(ow[4], ow[5]);
                d2[3] = make_uint2(ow[6], ow[7]);
            }
        }
    }
    // fragment loads: rows staged by THIS wave (tid=2r..2r+1 in wave w) -> no barrier
    uint2 fsrA[2], fsrB[2], fvrA[3], fvrB[3];
    #pragma unroll
    for (int jt = 0; jt < 2; jt++) {
        fsrA[jt] = *reinterpret_cast<const uint2*>(&Fns[eb0 * 40 + jt * 16 + lg * 4]);
        fsrB[jt] = *reinterpret_cast<const uint2*>(&Fns[eb1 * 40 + jt * 16 + lg * 4]);
    }
    #pragma unroll
    for (int i = 0; i < 3; i++) {
        const unsigned short* FnvI = (i == 0) ? Fnv0 : ((i == 1) ? Fnv1 : Fnv2);
        fvrA[i] = *reinterpret_cast<const uint2*>(&FnvI[eb0 * 20 + lg * 4]);
        fvrB[i] = *reinterpret_cast<const uint2*>(&FnvI[eb1 * 20 + lg * 4]);
    }
    __syncthreads();   // B5: WLT visible; Fns/Fnv regions dead (M may overwrite)

    // ---- pack fac (jt 1..5) to fp16 ----
    uint2 fpA[5], fpB[5];
    #pragma unroll
    for (int jt = 1; jt < 6; jt++) {
        fpA[jt - 1] = make_uint2(hpack2(fac0[jt][0], fac0[jt][1]), hpack2(fac0[jt][2], fac0[jt][3]));
        fpB[jt - 1] = make_uint2(hpack2(fac1[jt][0], fac1[jt][1]), hpack2(fac1[jt][2], fac1[jt][3]));
    }

    // ---- M_s fill ----
    {
        float2 a0 = up2(fvrA[0].x), a1 = up2(fvrA[0].y);
        float2 b0 = up2(fvrA[1].x), b1 = up2(fvrA[1].y);
        float2 c0 = up2(fvrA[2].x), c1 = up2(fvrA[2].y);
        float2 d0 = up2(fvrB[0].x), d1 = up2(fvrB[0].y);
        float2 e0 = up2(fvrB[1].x), e1 = up2(fvrB[1].y);
        float2 g0 = up2(fvrB[2].x), g1 = up2(fvrB[2].y);
        float vA[4], vB[4];
        vA[0] = (a0.x*ev0a + b0.x*ev1a + c0.x*ev2a) * fac0[0][0];
        vA[1] = (a0.y*ev0a + b0.y*ev1a + c0.y*ev2a) * fac0[0][1];
        vA[2] = (a1.x*ev0a + b1.x*ev1a + c1.x*ev2a) * fac0[0][2];
        vA[3] = (a1.y*ev0a + b1.y*ev1a + c1.y*ev2a) * fac0[0][3];
        vB[0] = (d0.x*ev0b + e0.x*ev1b + g0.x*ev2b) * fac1[0][0];
        vB[1] = (d0.y*ev0b + e0.y*ev1b + g0.y*ev2b) * fac1[0][1];
        vB[2] = (d1.x*ev0b + e1.x*ev1b + g1.x*ev2b) * fac1[0][2];
        vB[3] = (d1.y*ev0b + e1.y*ev1b + g1.y*ev2b) * fac1[0][3];
        *(uint2*)&M[eb0 * 72 + lg * 4] = make_uint2(hpack2(vA[0], vA[1]), hpack2(vA[2], vA[3]));
        *(uint2*)&M[eb1 * 72 + lg * 4] = make_uint2(hpack2(vB[0], vB[1]), hpack2(vB[2], vB[3]));
    }
    #pragma unroll
    for (int jt = 1; jt < 3; jt++) {
        int c0 = jt * 16 + lg * 4;
        *(uint2*)&M[eb0 * 72 + c0] =
            make_uint2(pkmul(fsrA[jt-1].x, fpA[jt-1].x), pkmul(fsrA[jt-1].y, fpA[jt-1].y));
        *(uint2*)&M[eb1 * 72 + c0] =
            make_uint2(pkmul(fsrB[jt-1].x, fpB[jt-1].x), pkmul(fsrB[jt-1].y, fpB[jt-1].y));
    }
    *(uint2*)&M[eb0 * 72 + 48 + lg * 4] = make_uint2(0u, 0u);
    *(uint2*)&M[eb1 * 72 + 48 + lg * 4] = make_uint2(0u, 0u);

    // ---- ys GEMM ----
    f32x4 accS[2][2] = {{zero4, zero4}, {zero4, zero4}};
    #pragma unroll
    for (int kt = 0; kt < 2; kt++) {
        f16x8 b0 = *(const f16x8*)&M[eb0 * 72 + kt * 32 + lg * 8];
        f16x8 b1 = *(const f16x8*)&M[eb1 * 72 + kt * 32 + lg * 8];
        #pragma unroll
        for (int ot = 0; ot < 2; ot++) {
            f16x8 a = *(const f16x8*)&sWLT[(ot * 16 + lr) * 72 + kt * 32 + lg * 8];
            accS[0][ot] = __builtin_amdgcn_mfma_f32_16x16x32_f16(a, b0, accS[0][ot], 0, 0, 0);
            accS[1][ot] = __builtin_amdgcn_mfma_f32_16x16x32_f16(a, b1, accS[1][ot], 0, 0, 0);
        }
    }

    // ---- T1 ----
    #pragma unroll
    for (int jt = 0; jt < 2; jt++) {
        int c0 = jt * 16 + lg * 4;
        *(uint2*)&M[eb0 * 72 + c0] =
            make_uint2(pkmul(fsrA[jt].x, fpA[jt+2].x), pkmul(fsrA[jt].y, fpA[jt+2].y));
        *(uint2*)&M[eb1 * 72 + c0] =
            make_uint2(pkmul(fsrB[jt].x, fpB[jt+2].x), pkmul(fsrB[jt].y, fpB[jt+2].y));
    }
    f32x4 t1A = zero4, t1B = zero4;
    {
        f16x8 b0 = *(const f16x8*)&M[eb0 * 72 + lg * 8];
        f16x8 b1 = *(const f16x8*)&M[eb1 * 72 + lg * 8];
        f16x8 a  = *(const f16x8*)&sWLT[(32 + lr) * 72 + lg * 8];
        t1A = __builtin_amdgcn_mfma_f32_16x16x32_f16(a, b0, t1A, 0, 0, 0);
        t1B = __builtin_amdgcn_mfma_f32_16x16x32_f16(a, b1, t1B, 0, 0, 0);
    }

    // ---- T2_i + combine ----
    float yvA[4][3], yvB[4][3];
    *(uint2*)&M[eb0 * 72 + 16 + lg * 4] = make_uint2(0u, 0u);
    *(uint2*)&M[eb1 * 72 + 16 + lg * 4] = make_uint2(0u, 0u);
    #pragma unroll
    for (int i = 0; i < 3; i++) {
        *(uint2*)&M[eb0 * 72 + lg * 4] =
            make_uint2(pkmul(fvrA[i].x, fpA[4].x), pkmul(fvrA[i].y, fpA[4].y));
        *(uint2*)&M[eb1 * 72 + lg * 4] =
            make_uint2(pkmul(fvrB[i].x, fpB[4].x), pkmul(fvrB[i].y, fpB[4].y));

        f32x4 t2A = zero4, t2B = zero4;
        f16x8 b0 = *(const f16x8*)&M[eb0 * 72 + lg * 8];
        f16x8 b1 = *(const f16x8*)&M[eb1 * 72 + lg * 8];
        f16x8 a  = *(const f16x8*)&sWLT[(32 + lr) * 72 + 32 + lg * 8];
        t2A = __builtin_amdgcn_mfma_f32_16x16x32_f16(a, b0, t2A, 0, 0, 0);
        t2B = __builtin_amdgcn_mfma_f32_16x16x32_f16(a, b1, t2B, 0, 0, 0);

        float evA = (i == 0) ? ev0a : ((i == 1) ? ev1a : ev2a);
        float evB = (i == 0) ? ev0b : ((i == 1) ? ev1b : ev2b);
        #pragma unroll
        for (int q = 0; q < 4; q++) {
            yvA[q][i] = fmaf(evA, t1A[q], t2A[q]);
            yvB[q][i] = fmaf(evB, t1B[q], t2B[q]);
        }
    }

    // ================= phase C: in-block segmented reduction ================
    __syncthreads();   // B6: M/WLT dead before redh overwrite

    {
        bool okA = (pA < p1), okB = (pB < p1);
        #pragma unroll
        for (int ot = 0; ot < 2; ot++) {
            f32x4 sA = okA ? accS[0][ot] : zero4;
            f32x4 sB = okB ? accS[1][ot] : zero4;
            *(uint2*)&redh[eb0 * 84 + ot * 16 + lg * 4] =
                make_uint2(hpack2(sA[0], sA[1]), hpack2(sA[2], sA[3]));
            *(uint2*)&redh[eb1 * 84 + ot * 16 + lg * 4] =
                make_uint2(hpack2(sB[0], sB[1]), hpack2(sB[2], sB[3]));
        }
        float zA[12], zB[12];
        #pragma unroll
        for (int q = 0; q < 4; q++)
            #pragma unroll
            for (int i = 0; i < 3; i++) {
                zA[3*q+i] = okA ? yvA[q][i] : 0.0f;
                zB[3*q+i] = okB ? yvB[q][i] : 0.0f;
            }
        uint2* dA = (uint2*)&redh[eb0 * 84 + 32 + 12 * lg];
        dA[0] = make_uint2(hpack2(zA[0], zA[1]),  hpack2(zA[2], zA[3]));
        dA[1] = make_uint2(hpack2(zA[4], zA[5]),  hpack2(zA[6], zA[7]));
        dA[2] = make_uint2(hpack2(zA[8], zA[9]),  hpack2(zA[10], zA[11]));
        uint2* dB = (uint2*)&redh[eb1 * 84 + 32 + 12 * lg];
        dB[0] = make_uint2(hpack2(zB[0], zB[1]),  hpack2(zB[2], zB[3]));
        dB[1] = make_uint2(hpack2(zB[4], zB[5]),  hpack2(zB[6], zB[7]));
        dB[2] = make_uint2(hpack2(zB[8], zB[9]),  hpack2(zB[10], zB[11]));
    }
    __syncthreads();   // B6b (wave-local reads below span this wave's rows only,
                       //  but redh writes above are wave-local too; keep for safety)

    // wave w reduces its own 32 rows; dst of row r via shfl from lane 2r
    {
        int base = w * 32;
        int cur = __shfl(dS, 0);
        float s0 = 0.0f, s1 = 0.0f;
        for (int r = 0; r < 32; r++) {
            int d = __shfl(dS, 2 * r);
            if (d != cur) {
                atomicAdd(&out[(size_t)cur * OUT_PER_NODE + lane], s0);
                if (lane < 16) atomicAdd(&out[(size_t)cur * OUT_PER_NODE + 64 + lane], s1);
                s0 = 0.0f; s1 = 0.0f; cur = d;
            }
            const unsigned short* row = &redh[(base + r) * 84];
            s0 += h2f(row[lane]);
            if (lane < 16) s1 += h2f(row[64 + lane]);
        }
        atomicAdd(&out[(size_t)cur * OUT_PER_NODE + lane], s0);
        if (lane < 16) atomicAdd(&out[(size_t)cur * OUT_PER_NODE + 64 + lane], s1);
    }
}

// ---------------------------------------------------------------------------
extern "C" void kernel_launch(void* const* d_in, const int* in_sizes, int n_in,
                              void* d_out, int out_size, void* d_ws, size_t ws_size,
                              hipStream_t stream) {
    const int*   esrc = (const int*)  d_in[0];
    const int*   edst = (const int*)  d_in[1];
    const float* ecut = (const float*)d_in[2];
    const float* einv = (const float*)d_in[3];
    const float* ns   = (const float*)d_in[4];
    const float* nv   = (const float*)d_in[5];
    const float* esh  = (const float*)d_in[6];
    const float* W0   = (const float*)d_in[7];
    const float* W1   = (const float*)d_in[8];
    const float* W2   = (const float*)d_in[9];
    const float* WLs  = (const float*)d_in[10];
    const float* WLv  = (const float*)d_in[11];
    float* out = (float*)d_out;

    const int E  = in_sizes[0];
    const int Nn = in_sizes[4] / S_IN;

    size_t int_bytes = (((size_t)(2 * Nn)) * sizeof(int) + 255) & ~(size_t)255;
    size_t pe_bytes  = ((size_t)E * 48 + 255) & ~(size_t)255;
    size_t pw_bytes  = ((size_t)PWTOT * 2 + 255) & ~(size_t)255;
    size_t ns_bytes  = ((size_t)Nn * 32 * 2 + 255) & ~(size_t)255;
    size_t nv_bytes  = ((size_t)Nn * 48 * 2 + 255) & ~(size_t)255;
    size_t fixed = int_bytes + pe_bytes + pw_bytes + ns_bytes + nv_bytes;

    int eblocks = (E + 255) / 256;

    hipMemsetAsync(out, 0, (size_t)Nn * OUT_PER_NODE * sizeof(float), stream);

    if (ws_size < fixed) return;

    int*            deg    = (int*)d_ws;
    int*            cursor = deg + Nn;          // Nn
    uint4*          pedge  = (uint4*)((char*)d_ws + int_bytes);
    unsigned short* pW     = (unsigned short*)((char*)d_ws + int_bytes + pe_bytes);
    unsigned short* pNS    = (unsigned short*)((char*)d_ws + int_bytes + pe_bytes + pw_bytes);
    unsigned short* pNV    = (unsigned short*)((char*)d_ws + int_bytes + pe_bytes + pw_bytes + ns_bytes);

    hipMemsetAsync(deg, 0, (size_t)Nn * sizeof(int), stream);

    int ptotal = PWTOT + Nn * 4 + Nn * 6;
    int hp_blocks = max(eblocks, (ptotal + 255) / 256);
    hist_prep<<<hp_blocks, 256, 0, stream>>>(edst, deg, E, W0, W1, W2, WLs, WLv,
                                             ns, nv, pW, pNS, pNV, Nn);
    scan1<<<1, 1024, 0, stream>>>(deg, cursor, Nn);
    scatter_permute<<<eblocks, 256, 0, stream>>>(edst, esrc, ecut, esh, einv,
                                                 cursor, pedge, E);

    int mblocks = (E + 127) / 128;
    edge_mega<<<mblocks, 256, 0, stream>>>(pedge, pW, pNS, pNV, out, E);
}

// Round 19
// 201.545 us; speedup vs baseline: 1.3370x; 1.3370x over previous
//
#include <hip/hip_runtime.h>
#include <hip/hip_fp16.h>
#include <math.h>

// Problem constants
constexpr int S_IN = 32, V_IN = 16, INVD = 16;
constexpr int S_MSG = S_IN + V_IN;           // 48
constexpr int V_MSG = S_IN + V_IN;           // 48
constexpr int NFAC  = S_MSG + V_MSG;         // 96
constexpr int S_OUT = 32, V_OUT = 16;
constexpr int OUT_PER_NODE = S_OUT + V_OUT * 3;  // 80
constexpr float ISQRT3 = 0.57735026918962576f;
constexpr float ISQ48  = 0.14433756729740643f;

// prepped-weight layout (in shorts): W0T[64][40] | W1T[64][72] | W2T[96][72] | WLT[48][72]
constexpr int PW0 = 0, PW1 = 2560, PW2 = 7168, PWL = 14080, PWTOT = 17536;

typedef _Float16 f16x8 __attribute__((ext_vector_type(8)));
typedef __attribute__((ext_vector_type(4))) float f32x4;

__device__ __forceinline__ float silu_f(float x) {
    return x * __builtin_amdgcn_rcpf(1.0f + __expf(-x));
}
__device__ __forceinline__ unsigned int hpack2(float a, float b) {
    __half2 h = __floats2half2_rn(a, b);        // v_cvt_pkrtz_f16_f32
    return *reinterpret_cast<unsigned int*>(&h);
}
__device__ __forceinline__ unsigned short f2h(float f) {
    __half h = __float2half_rn(f);
    return __half_as_ushort(h);
}
__device__ __forceinline__ float h2f(unsigned short u) {
    return __half2float(__ushort_as_half(u));
}
__device__ __forceinline__ float lo16f(unsigned int u) { return h2f((unsigned short)(u & 0xffffu)); }
__device__ __forceinline__ float hi16f(unsigned int u) { return h2f((unsigned short)(u >> 16)); }
__device__ __forceinline__ unsigned int pkmul(unsigned int a, unsigned int b) {
    __half2 ha = *reinterpret_cast<__half2*>(&a);
    __half2 hb = *reinterpret_cast<__half2*>(&b);
    __half2 hc = __hmul2(ha, hb);               // v_pk_mul_f16
    return *reinterpret_cast<unsigned int*>(&hc);
}
__device__ __forceinline__ float2 up2(unsigned int u) {
    __half2 h = *reinterpret_cast<__half2*>(&u);
    return __half22float2(h);
}

// ---------------------------------------------------------------------------
// hist + prep fused
// ---------------------------------------------------------------------------
__global__ __launch_bounds__(256) void hist_prep(
    const int* __restrict__ edst, int* __restrict__ deg, int E,
    const float* __restrict__ W0, const float* __restrict__ W1,
    const float* __restrict__ W2, const float* __restrict__ WLs,
    const float* __restrict__ WLv,
    const float* __restrict__ ns, const float* __restrict__ nv,
    unsigned short* __restrict__ pW,
    unsigned short* __restrict__ pNS,
    unsigned short* __restrict__ pNV,
    int Nn)
{
    int i = blockIdx.x * 256 + threadIdx.x;
    if (i < E) atomicAdd(&deg[edst[i]], 1);

    int nNS = Nn * 4;
    int nNV = Nn * 6;
    if (i < PWTOT) {
        float v = 0.0f;
        if (i < PW1) {
            int j = i / 40, k = i - 40 * j;
            if (k < INVD) v = W0[k * 64 + j];
        } else if (i < PW2) {
            int t = i - PW1; int j = t / 72, k = t - 72 * j;
            if (k < 64) v = W1[k * 64 + j];
        } else if (i < PWL) {
            int t = i - PW2; int j = t / 72, k = t - 72 * j;
            if (k < 64) v = W2[k * 96 + j];
        } else {
            int t = i - PWL; int j = t / 72, k = t - 72 * j;
            if (k < 48) v = (j < 32) ? WLs[k * S_OUT + j] : WLv[k * V_OUT + (j - 32)];
        }
        pW[i] = f2h(v);
    } else if (i < PWTOT + nNS) {
        int g = i - PWTOT;
        const float4* s4 = reinterpret_cast<const float4*>(ns + (size_t)g * 8);
        float4 a = s4[0], b = s4[1];
        *reinterpret_cast<uint4*>(pNS + (size_t)g * 8) =
            make_uint4(hpack2(a.x, a.y), hpack2(a.z, a.w), hpack2(b.x, b.y), hpack2(b.z, b.w));
    } else if (i < PWTOT + nNS + nNV) {
        int g = i - PWTOT - nNS;
        const float4* s4 = reinterpret_cast<const float4*>(nv + (size_t)g * 8);
        float4 a = s4[0], b = s4[1];
        *reinterpret_cast<uint4*>(pNV + (size_t)g * 8) =
            make_uint4(hpack2(a.x, a.y), hpack2(a.z, a.w), hpack2(b.x, b.y), hpack2(b.z, b.w));
    }
}

// ---------------------------------------------------------------------------
// 3-kernel parallel scan (cursor only)
// ---------------------------------------------------------------------------
__global__ __launch_bounds__(256) void scanA(
    const int* __restrict__ deg, int* __restrict__ bsum, int Nn)
{
    __shared__ int sh[256];
    int i = blockIdx.x * 256 + threadIdx.x;
    sh[threadIdx.x] = (i < Nn) ? deg[i] : 0;
    __syncthreads();
    for (int o = 128; o > 0; o >>= 1) {
        if (threadIdx.x < o) sh[threadIdx.x] += sh[threadIdx.x + o];
        __syncthreads();
    }
    if (threadIdx.x == 0) bsum[blockIdx.x] = sh[0];
}

__global__ __launch_bounds__(1024) void scanB(int* __restrict__ bsum, int nb)
{
    __shared__ int sh[1024];
    int t = threadIdx.x;
    sh[t] = (t < nb) ? bsum[t] : 0;
    __syncthreads();
    for (int o = 1; o < 1024; o <<= 1) {
        int v = (t >= o) ? sh[t - o] : 0;
        __syncthreads();
        sh[t] += v;
        __syncthreads();
    }
    if (t < nb) bsum[t] = (t > 0) ? sh[t - 1] : 0;   // exclusive
}

__global__ __launch_bounds__(256) void scanC(
    const int* __restrict__ deg, const int* __restrict__ bsum,
    int* __restrict__ cursor, int Nn)
{
    __shared__ int sh[256];
    int i = blockIdx.x * 256 + threadIdx.x;
    int t = threadIdx.x;
    int v = (i < Nn) ? deg[i] : 0;
    sh[t] = v;
    __syncthreads();
    for (int o = 1; o < 256; o <<= 1) {
        int u = (t >= o) ? sh[t - o] : 0;
        __syncthreads();
        sh[t] += u;
        __syncthreads();
    }
    int excl = sh[t] - v + bsum[blockIdx.x];
    if (i < Nn) cursor[i] = excl;
}

// Fat scatter: 48B per-edge record at permuted position (3 x uint4).
// r0,r1 = einv f16 x16 (32B)
// r2 = { cut_h|esh0_h, esh1_h|esh2_h, src, dst } (16B)
__global__ __launch_bounds__(256) void scatter_permute(
    const int*   __restrict__ edst,
    const int*   __restrict__ esrc,
    const float* __restrict__ ecut,
    const float* __restrict__ esh,
    const float* __restrict__ einv,
    int* __restrict__ cursor,
    uint4* __restrict__ pedge,
    int E)
{
    int e = blockIdx.x * 256 + threadIdx.x;
    if (e >= E) return;
    int d = edst[e];
    int pos = atomicAdd(&cursor[d], 1);

    const float4* xr = reinterpret_cast<const float4*>(einv + (size_t)e * INVD);
    float4 a = xr[0], b = xr[1], c = xr[2], f = xr[3];
    uint4 r0 = make_uint4(hpack2(a.x, a.y), hpack2(a.z, a.w), hpack2(b.x, b.y), hpack2(b.z, b.w));
    uint4 r1 = make_uint4(hpack2(c.x, c.y), hpack2(c.z, c.w), hpack2(f.x, f.y), hpack2(f.z, f.w));
    uint4 r2 = make_uint4(hpack2(ecut[e], esh[(size_t)e * 3 + 0]),
                          hpack2(esh[(size_t)e * 3 + 1], esh[(size_t)e * 3 + 2]),
                          (unsigned int)esrc[e], (unsigned int)d);

    uint4* dst = pedge + (size_t)pos * 3;
    dst[0] = r0; dst[1] = r1; dst[2] = r2;
}

// ---------------------------------------------------------------------------
// MEGA kernel v10 (unchanged from round 18): 32 KiB LDS (5 blocks/CU);
// split prefetch; parallel phase-B staging; 7 barriers total.
// ---------------------------------------------------------------------------
__global__ __launch_bounds__(256, 5) void edge_mega(
    const uint4* __restrict__ pedge,
    const unsigned short* __restrict__ pW,
    const unsigned short* __restrict__ pNS,
    const unsigned short* __restrict__ pNV,
    float* __restrict__ out,
    int E)
{
    __shared__ __align__(16) unsigned char smem[32768];

    unsigned short* act  = (unsigned short*)(smem + 0);      // [128][72]
    unsigned short* sW0T = (unsigned short*)(smem + 18432);  // [64][40]
    unsigned short* sW1T = (unsigned short*)(smem + 23552);  // [64][72]
    unsigned short* sW2T = (unsigned short*)(smem + 18432);  // [96][72]
    unsigned short* sWLT = (unsigned short*)(smem + 0);      // [48][72]
    unsigned short* Fns  = (unsigned short*)(smem + 6912);   // [128][40]
    unsigned short* Fnv0 = (unsigned short*)(smem + 17152);  // [128][20]
    unsigned short* Fnv1 = (unsigned short*)(smem + 22272);  // [128][20]
    unsigned short* Fnv2 = (unsigned short*)(smem + 27392);  // [128][20]
    unsigned short* M    = (unsigned short*)(smem + 6912);   // [128][72]
    unsigned short* redh = (unsigned short*)(smem + 0);      // [128][84] fp16

    const int tid = threadIdx.x;
    const int pbase = blockIdx.x * 128;
    const int p1 = E;

    const int lane = tid & 63;
    const int w    = tid >> 6;
    const int lr   = lane & 15;
    const int lg   = lane >> 4;
    const int eb0  = w * 32 + lr;
    const int eb1  = eb0 + 16;
    const int pA   = pbase + eb0;
    const int pB   = pbase + eb1;

    // ============ PREFETCH (split: half=0 -> ns row, half=1 -> nv row) ======
    const uint4 rA2 = pedge[(size_t)(pA < p1 ? pA : p1 - 1) * 3 + 2];
    const uint4 rB2 = pedge[(size_t)(pB < p1 ? pB : p1 - 1) * 3 + 2];
    const float cutA = lo16f(rA2.x);
    const float ev0a = hi16f(rA2.x), ev1a = lo16f(rA2.y), ev2a = hi16f(rA2.y);
    const float cutB = lo16f(rB2.x);
    const float ev0b = hi16f(rB2.x), ev1b = lo16f(rB2.y), ev2b = hi16f(rB2.y);

    const int t2 = tid >> 1, half = tid & 1;
    int dS;
    uint4 pf0, pf1, pf2, pf3, pf4, pf5;
    {
        int pS = pbase + t2; if (pS >= p1) pS = p1 - 1;
        uint4 r2 = pedge[(size_t)pS * 3 + 2];
        int sS = (int)r2.z;
        dS = (int)r2.w;
        if (half == 0) {
            const uint4* nr = reinterpret_cast<const uint4*>(pNS + (size_t)sS * 32);
            pf0 = nr[0]; pf1 = nr[1]; pf2 = nr[2]; pf3 = nr[3];
        } else {
            const uint4* vr = reinterpret_cast<const uint4*>(pNV + (size_t)sS * 48);
            pf0 = vr[0]; pf1 = vr[1]; pf2 = vr[2]; pf3 = vr[3]; pf4 = vr[4]; pf5 = vr[5];
        }
    }

    const uint4* wsrc = reinterpret_cast<const uint4*>(pW);

    // ---- stage W0T+W1T (896 uint4) + X into act ----
    {
        uint4* s4 = reinterpret_cast<uint4*>(smem + 18432);
        #pragma unroll 2
        for (int i = tid; i < 896; i += 256) s4[i] = wsrc[i];
    }
    if (tid < 128) {
        int p = pbase + tid; if (p >= p1) p = p1 - 1;
        const uint4* rec = pedge + (size_t)p * 3;
        uint4 r0 = rec[0], r1 = rec[1];
        uint4* r4 = reinterpret_cast<uint4*>(&act[tid * 72]);
        r4[0] = r0;
        r4[1] = r1;
        r4[2] = make_uint4(0u, 0u, 0u, 0u);
        r4[3] = make_uint4(0u, 0u, 0u, 0u);
    }
    __syncthreads();   // B1

    const f32x4 zero4 = {0.f, 0.f, 0.f, 0.f};

    // ---- Layer 1: h1 = silu((X@W0)/4); wave-local ----
    {
        f16x8 b0 = *(const f16x8*)&act[eb0 * 72 + lg * 8];
        f16x8 b1 = *(const f16x8*)&act[eb1 * 72 + lg * 8];
        #pragma unroll
        for (int jt = 0; jt < 4; jt++) {
            f16x8 a = *(const f16x8*)&sW0T[(jt * 16 + lr) * 40 + lg * 8];
            f32x4 d0 = __builtin_amdgcn_mfma_f32_16x16x32_f16(a, b0, zero4, 0, 0, 0);
            f32x4 d1 = __builtin_amdgcn_mfma_f32_16x16x32_f16(a, b1, zero4, 0, 0, 0);
            unsigned int u0 = hpack2(silu_f(d0[0] * 0.25f), silu_f(d0[1] * 0.25f));
            unsigned int u1 = hpack2(silu_f(d0[2] * 0.25f), silu_f(d0[3] * 0.25f));
            *(uint2*)&act[eb0 * 72 + jt * 16 + lg * 4] = make_uint2(u0, u1);
            u0 = hpack2(silu_f(d1[0] * 0.25f), silu_f(d1[1] * 0.25f));
            u1 = hpack2(silu_f(d1[2] * 0.25f), silu_f(d1[3] * 0.25f));
            *(uint2*)&act[eb1 * 72 + jt * 16 + lg * 4] = make_uint2(u0, u1);
        }
    }

    // ---- Layer 2: h2 = silu((h1@W1)/8); wave-local ----
    {
        f16x8 b00 = *(const f16x8*)&act[eb0 * 72 +      lg * 8];
        f16x8 b01 = *(const f16x8*)&act[eb0 * 72 + 32 + lg * 8];
        f16x8 b10 = *(const f16x8*)&act[eb1 * 72 +      lg * 8];
        f16x8 b11 = *(const f16x8*)&act[eb1 * 72 + 32 + lg * 8];
        #pragma unroll
        for (int jt = 0; jt < 4; jt++) {
            f16x8 a0 = *(const f16x8*)&sW1T[(jt * 16 + lr) * 72 +      lg * 8];
            f16x8 a1 = *(const f16x8*)&sW1T[(jt * 16 + lr) * 72 + 32 + lg * 8];
            f32x4 d0 = __builtin_amdgcn_mfma_f32_16x16x32_f16(a0, b00, zero4, 0, 0, 0);
            d0 = __builtin_amdgcn_mfma_f32_16x16x32_f16(a1, b01, d0, 0, 0, 0);
            f32x4 d1 = __builtin_amdgcn_mfma_f32_16x16x32_f16(a0, b10, zero4, 0, 0, 0);
            d1 = __builtin_amdgcn_mfma_f32_16x16x32_f16(a1, b11, d1, 0, 0, 0);
            unsigned int u0 = hpack2(silu_f(d0[0] * 0.125f), silu_f(d0[1] * 0.125f));
            unsigned int u1 = hpack2(silu_f(d0[2] * 0.125f), silu_f(d0[3] * 0.125f));
            *(uint2*)&act[eb0 * 72 + jt * 16 + lg * 4] = make_uint2(u0, u1);
            u0 = hpack2(silu_f(d1[0] * 0.125f), silu_f(d1[1] * 0.125f));
            u1 = hpack2(silu_f(d1[2] * 0.125f), silu_f(d1[3] * 0.125f));
            *(uint2*)&act[eb1 * 72 + jt * 16 + lg * 4] = make_uint2(u0, u1);
        }
    }

    __syncthreads();   // B2: W0T/W1T reads done
    {
        uint4* a14 = reinterpret_cast<uint4*>(smem + 18432);
        const uint4* w2s = wsrc + 896;
        #pragma unroll 2
        for (int i = tid; i < 864; i += 256) a14[i] = w2s[i];
    }
    __syncthreads();   // B3: W2T staged

    // ---- Layer 3: fac -> registers ----
    float fac0[6][4], fac1[6][4];
    {
        f16x8 b00 = *(const f16x8*)&act[eb0 * 72 +      lg * 8];
        f16x8 b01 = *(const f16x8*)&act[eb0 * 72 + 32 + lg * 8];
        f16x8 b10 = *(const f16x8*)&act[eb1 * 72 +      lg * 8];
        f16x8 b11 = *(const f16x8*)&act[eb1 * 72 + 32 + lg * 8];
        float K0 = cutA * 0.125f * ISQ48;
        float K1 = cutB * 0.125f * ISQ48;
        #pragma unroll
        for (int jt = 0; jt < 6; jt++) {
            f16x8 a0 = *(const f16x8*)&sW2T[(jt * 16 + lr) * 72 +      lg * 8];
            f16x8 a1 = *(const f16x8*)&sW2T[(jt * 16 + lr) * 72 + 32 + lg * 8];
            f32x4 d0 = __builtin_amdgcn_mfma_f32_16x16x32_f16(a0, b00, zero4, 0, 0, 0);
            d0 = __builtin_amdgcn_mfma_f32_16x16x32_f16(a1, b01, d0, 0, 0, 0);
            f32x4 d1 = __builtin_amdgcn_mfma_f32_16x16x32_f16(a0, b10, zero4, 0, 0, 0);
            d1 = __builtin_amdgcn_mfma_f32_16x16x32_f16(a1, b11, d1, 0, 0, 0);
            float s0 = (jt == 0) ? K0 * ISQRT3 : K0;
            float s1 = (jt == 0) ? K1 * ISQRT3 : K1;
            #pragma unroll
            for (int q = 0; q < 4; q++) {
                fac0[jt][q] = d0[q] * s0;
                fac1[jt][q] = d1[q] * s1;
            }
        }
    }
    __syncthreads();   // B4: act + W2T dead

    // ---- PARALLEL stage: WLT (all threads) + Fns (half=0) + Fnv (half=1) ----
    {
        uint4* wl4 = reinterpret_cast<uint4*>(smem);           // WLT @0
        const uint4* wls = wsrc + 896 + 864;
        #pragma unroll 2
        for (int i = tid; i < 432; i += 256) wl4[i] = wls[i];

        if (half == 0) {
            uint4* d4 = reinterpret_cast<uint4*>(&Fns[t2 * 40]);
            d4[0] = pf0; d4[1] = pf1;
            uint4* d4b = reinterpret_cast<uint4*>(&Fns[t2 * 40 + 16]);
            d4b[0] = pf2; d4b[1] = pf3;
        } else {
            unsigned int wb[24];
            wb[0]=pf0.x; wb[1]=pf0.y; wb[2]=pf0.z; wb[3]=pf0.w;
            wb[4]=pf1.x; wb[5]=pf1.y; wb[6]=pf1.z; wb[7]=pf1.w;
            wb[8]=pf2.x; wb[9]=pf2.y; wb[10]=pf2.z; wb[11]=pf2.w;
            wb[12]=pf3.x; wb[13]=pf3.y; wb[14]=pf3.z; wb[15]=pf3.w;
            wb[16]=pf4.x; wb[17]=pf4.y; wb[18]=pf4.z; wb[19]=pf4.w;
            wb[20]=pf5.x; wb[21]=pf5.y; wb[22]=pf5.z; wb[23]=pf5.w;
            #pragma unroll
            for (int i = 0; i < 3; i++) {
                unsigned short* FnvI = (i == 0) ? Fnv0 : ((i == 1) ? Fnv1 : Fnv2);
                unsigned int ow[8];
                #pragma unroll
                for (int wd = 0; wd < 8; wd++) {
                    int kLo = 6 * wd + i;
                    int kHi = 6 * wd + 3 + i;
                    unsigned int lo = (kLo & 1) ? (wb[kLo >> 1] >> 16) : (wb[kLo >> 1] & 0xffffu);
                    unsigned int hi = (kHi & 1) ? (wb[kHi >> 1] >> 16) : (wb[kHi >> 1] & 0xffffu);
                    ow[wd] = lo | (hi << 16);
                }
                uint2* d2 = reinterpret_cast<uint2*>(&FnvI[t2 * 20]);
                d2[0] = make_uint2(ow[0], ow[1]);
                d2[1] = make_uint2(ow[2], ow[3]);
                d2[2] = make_uint2(ow[4], ow[5]);
                d2[3] = make_uint2(ow[6], ow[7]);
            }
        }
    }
    // fragment loads: rows staged by THIS wave -> no barrier needed
    uint2 fsrA[2], fsrB[2], fvrA[3], fvrB[3];
    #pragma unroll
    for (int jt = 0; jt < 2; jt++) {
        fsrA[jt] = *reinterpret_cast<const uint2*>(&Fns[eb0 * 40 + jt * 16 + lg * 4]);
        fsrB[jt] = *reinterpret_cast<const uint2*>(&Fns[eb1 * 40 + jt * 16 + lg * 4]);
    }
    #pragma unroll
    for (int i = 0; i < 3; i++) {
        const unsigned short* FnvI = (i == 0) ? Fnv0 : ((i == 1) ? Fnv1 : Fnv2);
        fvrA[i] = *reinterpret_cast<const uint2*>(&FnvI[eb0 * 20 + lg * 4]);
        fvrB[i] = *reinterpret_cast<const uint2*>(&FnvI[eb1 * 20 + lg * 4]);
    }
    __syncthreads();   // B5: WLT visible; Fns/Fnv regions dead (M may overwrite)

    // ---- pack fac (jt 1..5) to fp16 ----
    uint2 fpA[5], fpB[5];
    #pragma unroll
    for (int jt = 1; jt < 6; jt++) {
        fpA[jt - 1] = make_uint2(hpack2(fac0[jt][0], fac0[jt][1]), hpack2(fac0[jt][2], fac0[jt][3]));
        fpB[jt - 1] = make_uint2(hpack2(fac1[jt][0], fac1[jt][1]), hpack2(fac1[jt][2], fac1[jt][3]));
    }

    // ---- M_s fill ----
    {
        float2 a0 = up2(fvrA[0].x), a1 = up2(fvrA[0].y);
        float2 b0 = up2(fvrA[1].x), b1 = up2(fvrA[1].y);
        float2 c0 = up2(fvrA[2].x), c1 = up2(fvrA[2].y);
        float2 d0 = up2(fvrB[0].x), d1 = up2(fvrB[0].y);
        float2 e0 = up2(fvrB[1].x), e1 = up2(fvrB[1].y);
        float2 g0 = up2(fvrB[2].x), g1 = up2(fvrB[2].y);
        float vA[4], vB[4];
        vA[0] = (a0.x*ev0a + b0.x*ev1a + c0.x*ev2a) * fac0[0][0];
        vA[1] = (a0.y*ev0a + b0.y*ev1a + c0.y*ev2a) * fac0[0][1];
        vA[2] = (a1.x*ev0a + b1.x*ev1a + c1.x*ev2a) * fac0[0][2];
        vA[3] = (a1.y*ev0a + b1.y*ev1a + c1.y*ev2a) * fac0[0][3];
        vB[0] = (d0.x*ev0b + e0.x*ev1b + g0.x*ev2b) * fac1[0][0];
        vB[1] = (d0.y*ev0b + e0.y*ev1b + g0.y*ev2b) * fac1[0][1];
        vB[2] = (d1.x*ev0b + e1.x*ev1b + g1.x*ev2b) * fac1[0][2];
        vB[3] = (d1.y*ev0b + e1.y*ev1b + g1.y*ev2b) * fac1[0][3];
        *(uint2*)&M[eb0 * 72 + lg * 4] = make_uint2(hpack2(vA[0], vA[1]), hpack2(vA[2], vA[3]));
        *(uint2*)&M[eb1 * 72 + lg * 4] = make_uint2(hpack2(vB[0], vB[1]), hpack2(vB[2], vB[3]));
    }
    #pragma unroll
    for (int jt = 1; jt < 3; jt++) {
        int c0 = jt * 16 + lg * 4;
        *(uint2*)&M[eb0 * 72 + c0] =
            make_uint2(pkmul(fsrA[jt-1].x, fpA[jt-1].x), pkmul(fsrA[jt-1].y, fpA[jt-1].y));
        *(uint2*)&M[eb1 * 72 + c0] =
            make_uint2(pkmul(fsrB[jt-1].x, fpB[jt-1].x), pkmul(fsrB[jt-1].y, fpB[jt-1].y));
    }
    *(uint2*)&M[eb0 * 72 + 48 + lg * 4] = make_uint2(0u, 0u);
    *(uint2*)&M[eb1 * 72 + 48 + lg * 4] = make_uint2(0u, 0u);

    // ---- ys GEMM ----
    f32x4 accS[2][2] = {{zero4, zero4}, {zero4, zero4}};
    #pragma unroll
    for (int kt = 0; kt < 2; kt++) {
        f16x8 b0 = *(const f16x8*)&M[eb0 * 72 + kt * 32 + lg * 8];
        f16x8 b1 = *(const f16x8*)&M[eb1 * 72 + kt * 32 + lg * 8];
        #pragma unroll
        for (int ot = 0; ot < 2; ot++) {
            f16x8 a = *(const f16x8*)&sWLT[(ot * 16 + lr) * 72 + kt * 32 + lg * 8];
            accS[0][ot] = __builtin_amdgcn_mfma_f32_16x16x32_f16(a, b0, accS[0][ot], 0, 0, 0);
            accS[1][ot] = __builtin_amdgcn_mfma_f32_16x16x32_f16(a, b1, accS[1][ot], 0, 0, 0);
        }
    }

    // ---- T1 ----
    #pragma unroll
    for (int jt = 0; jt < 2; jt++) {
        int c0 = jt * 16 + lg * 4;
        *(uint2*)&M[eb0 * 72 + c0] =
            make_uint2(pkmul(fsrA[jt].x, fpA[jt+2].x), pkmul(fsrA[jt].y, fpA[jt+2].y));
        *(uint2*)&M[eb1 * 72 + c0] =
            make_uint2(pkmul(fsrB[jt].x, fpB[jt+2].x), pkmul(fsrB[jt].y, fpB[jt+2].y));
    }
    f32x4 t1A = zero4, t1B = zero4;
    {
        f16x8 b0 = *(const f16x8*)&M[eb0 * 72 + lg * 8];
        f16x8 b1 = *(const f16x8*)&M[eb1 * 72 + lg * 8];
        f16x8 a  = *(const f16x8*)&sWLT[(32 + lr) * 72 + lg * 8];
        t1A = __builtin_amdgcn_mfma_f32_16x16x32_f16(a, b0, t1A, 0, 0, 0);
        t1B = __builtin_amdgcn_mfma_f32_16x16x32_f16(a, b1, t1B, 0, 0, 0);
    }

    // ---- T2_i + combine ----
    float yvA[4][3], yvB[4][3];
    *(uint2*)&M[eb0 * 72 + 16 + lg * 4] = make_uint2(0u, 0u);
    *(uint2*)&M[eb1 * 72 + 16 + lg * 4] = make_uint2(0u, 0u);
    #pragma unroll
    for (int i = 0; i < 3; i++) {
        *(uint2*)&M[eb0 * 72 + lg * 4] =
            make_uint2(pkmul(fvrA[i].x, fpA[4].x), pkmul(fvrA[i].y, fpA[4].y));
        *(uint2*)&M[eb1 * 72 + lg * 4] =
            make_uint2(pkmul(fvrB[i].x, fpB[4].x), pkmul(fvrB[i].y, fpB[4].y));

        f32x4 t2A = zero4, t2B = zero4;
        f16x8 b0 = *(const f16x8*)&M[eb0 * 72 + lg * 8];
        f16x8 b1 = *(const f16x8*)&M[eb1 * 72 + lg * 8];
        f16x8 a  = *(const f16x8*)&sWLT[(32 + lr) * 72 + 32 + lg * 8];
        t2A = __builtin_amdgcn_mfma_f32_16x16x32_f16(a, b0, t2A, 0, 0, 0);
        t2B = __builtin_amdgcn_mfma_f32_16x16x32_f16(a, b1, t2B, 0, 0, 0);

        float evA = (i == 0) ? ev0a : ((i == 1) ? ev1a : ev2a);
        float evB = (i == 0) ? ev0b : ((i == 1) ? ev1b : ev2b);
        #pragma unroll
        for (int q = 0; q < 4; q++) {
            yvA[q][i] = fmaf(evA, t1A[q], t2A[q]);
            yvB[q][i] = fmaf(evB, t1B[q], t2B[q]);
        }
    }

    // ================= phase C: in-block segmented reduction ================
    __syncthreads();   // B6: M/WLT dead before redh overwrite

    {
        bool okA = (pA < p1), okB = (pB < p1);
        #pragma unroll
        for (int ot = 0; ot < 2; ot++) {
            f32x4 sA = okA ? accS[0][ot] : zero4;
            f32x4 sB = okB ? accS[1][ot] : zero4;
            *(uint2*)&redh[eb0 * 84 + ot * 16 + lg * 4] =
                make_uint2(hpack2(sA[0], sA[1]), hpack2(sA[2], sA[3]));
            *(uint2*)&redh[eb1 * 84 + ot * 16 + lg * 4] =
                make_uint2(hpack2(sB[0], sB[1]), hpack2(sB[2], sB[3]));
        }
        float zA[12], zB[12];
        #pragma unroll
        for (int q = 0; q < 4; q++)
            #pragma unroll
            for (int i = 0; i < 3; i++) {
                zA[3*q+i] = okA ? yvA[q][i] : 0.0f;
                zB[3*q+i] = okB ? yvB[q][i] : 0.0f;
            }
        uint2* dA = (uint2*)&redh[eb0 * 84 + 32 + 12 * lg];
        dA[0] = make_uint2(hpack2(zA[0], zA[1]),  hpack2(zA[2], zA[3]));
        dA[1] = make_uint2(hpack2(zA[4], zA[5]),  hpack2(zA[6], zA[7]));
        dA[2] = make_uint2(hpack2(zA[8], zA[9]),  hpack2(zA[10], zA[11]));
        uint2* dB = (uint2*)&redh[eb1 * 84 + 32 + 12 * lg];
        dB[0] = make_uint2(hpack2(zB[0], zB[1]),  hpack2(zB[2], zB[3]));
        dB[1] = make_uint2(hpack2(zB[4], zB[5]),  hpack2(zB[6], zB[7]));
        dB[2] = make_uint2(hpack2(zB[8], zB[9]),  hpack2(zB[10], zB[11]));
    }
    __syncthreads();   // B7

    // wave w reduces its own 32 rows; dst of row r via shfl from lane 2r
    {
        int base = w * 32;
        int cur = __shfl(dS, 0);
        float s0 = 0.0f, s1 = 0.0f;
        for (int r = 0; r < 32; r++) {
            int d = __shfl(dS, 2 * r);
            if (d != cur) {
                atomicAdd(&out[(size_t)cur * OUT_PER_NODE + lane], s0);
                if (lane < 16) atomicAdd(&out[(size_t)cur * OUT_PER_NODE + 64 + lane], s1);
                s0 = 0.0f; s1 = 0.0f; cur = d;
            }
            const unsigned short* row = &redh[(base + r) * 84];
            s0 += h2f(row[lane]);
            if (lane < 16) s1 += h2f(row[64 + lane]);
        }
        atomicAdd(&out[(size_t)cur * OUT_PER_NODE + lane], s0);
        if (lane < 16) atomicAdd(&out[(size_t)cur * OUT_PER_NODE + 64 + lane], s1);
    }
}

// ---------------------------------------------------------------------------
extern "C" void kernel_launch(void* const* d_in, const int* in_sizes, int n_in,
                              void* d_out, int out_size, void* d_ws, size_t ws_size,
                              hipStream_t stream) {
    const int*   esrc = (const int*)  d_in[0];
    const int*   edst = (const int*)  d_in[1];
    const float* ecut = (const float*)d_in[2];
    const float* einv = (const float*)d_in[3];
    const float* ns   = (const float*)d_in[4];
    const float* nv   = (const float*)d_in[5];
    const float* esh  = (const float*)d_in[6];
    const float* W0   = (const float*)d_in[7];
    const float* W1   = (const float*)d_in[8];
    const float* W2   = (const float*)d_in[9];
    const float* WLs  = (const float*)d_in[10];
    const float* WLv  = (const float*)d_in[11];
    float* out = (float*)d_out;

    const int E  = in_sizes[0];
    const int Nn = in_sizes[4] / S_IN;
    const int nb = (Nn + 255) / 256;

    size_t int_bytes = (((size_t)(2 * Nn + nb)) * sizeof(int) + 255) & ~(size_t)255;
    size_t pe_bytes  = ((size_t)E * 48 + 255) & ~(size_t)255;
    size_t pw_bytes  = ((size_t)PWTOT * 2 + 255) & ~(size_t)255;
    size_t ns_bytes  = ((size_t)Nn * 32 * 2 + 255) & ~(size_t)255;
    size_t nv_bytes  = ((size_t)Nn * 48 * 2 + 255) & ~(size_t)255;
    size_t fixed = int_bytes + pe_bytes + pw_bytes + ns_bytes + nv_bytes;

    int eblocks = (E + 255) / 256;

    hipMemsetAsync(out, 0, (size_t)Nn * OUT_PER_NODE * sizeof(float), stream);

    if (ws_size < fixed) return;

    int*            deg    = (int*)d_ws;
    int*            cursor = deg + Nn;          // Nn
    int*            bsum   = cursor + Nn;       // nb
    uint4*          pedge  = (uint4*)((char*)d_ws + int_bytes);
    unsigned short* pW     = (unsigned short*)((char*)d_ws + int_bytes + pe_bytes);
    unsigned short* pNS    = (unsigned short*)((char*)d_ws + int_bytes + pe_bytes + pw_bytes);
    unsigned short* pNV    = (unsigned short*)((char*)d_ws + int_bytes + pe_bytes + pw_bytes + ns_bytes);

    hipMemsetAsync(deg, 0, (size_t)Nn * sizeof(int), stream);

    int ptotal = PWTOT + Nn * 4 + Nn * 6;
    int hp_blocks = max(eblocks, (ptotal + 255) / 256);
    hist_prep<<<hp_blocks, 256, 0, stream>>>(edst, deg, E, W0, W1, W2, WLs, WLv,
                                             ns, nv, pW, pNS, pNV, Nn);
    scanA<<<nb, 256, 0, stream>>>(deg, bsum, Nn);
    scanB<<<1, 1024, 0, stream>>>(bsum, nb);
    scanC<<<nb, 256, 0, stream>>>(deg, bsum, cursor, Nn);
    scatter_permute<<<eblocks, 256, 0, stream>>>(edst, esrc, ecut, esh, einv,
                                                 cursor, pedge, E);

    int mblocks = (E + 127) / 128;
    edge_mega<<<mblocks, 256, 0, stream>>>(pedge, pW, pNS, pNV, out, E);
}